// Round 2
// baseline (105.164 us; speedup 1.0000x reference)
//
#include <hip/hip_runtime.h>

#define WPTS 801
#define ROWS_PER_BLOCK 16
#define BLOCK_THREADS 832   // 13 waves, covers 801 wavelengths

struct c2 { float x, y; };

__device__ __forceinline__ c2 c_add(c2 a, c2 b) { return {a.x + b.x, a.y + b.y}; }
__device__ __forceinline__ c2 c_sub(c2 a, c2 b) { return {a.x - b.x, a.y - b.y}; }
__device__ __forceinline__ c2 c_div(c2 a, c2 b) {
    float inv = 1.0f / (b.x * b.x + b.y * b.y);
    return {(a.x * b.x + a.y * b.y) * inv, (a.y * b.x - a.x * b.y) * inv};
}

__global__ __launch_bounds__(BLOCK_THREADS)
void kla_tmm_kernel(const float* __restrict__ d_phys,
                    const float* __restrict__ nSi_f,
                    const float* __restrict__ nSiO2_f,
                    const float* __restrict__ nSi3N4_f,
                    const float* __restrict__ lam,
                    float* __restrict__ out,
                    int B)
{
    __shared__ float sd[ROWS_PER_BLOCK * 7];

    const int tid = threadIdx.x;
    const int brow0 = blockIdx.x * ROWS_PER_BLOCK;
    const int nrows = min(ROWS_PER_BLOCK, B - brow0);

    // Stage this block's d_phys rows into LDS (nrows*7 <= 112 floats).
    if (tid < nrows * 7) sd[tid] = d_phys[(size_t)brow0 * 7 + tid];
    __syncthreads();

    const int w = tid;
    if (w >= WPTS) return;

    // ---- Layout-robust complex reads (scalar 4-byte loads only) ----
    // complex64 interleaved: floats = [re0, im0, re1, im1, ...]; im0 == 0 here.
    // real-only fallback:    floats = [re0, re1, ...];  nSiO2_f[1] = 1.46 != 0.
    const bool ilv = (nSiO2_f[1] == 0.0f);   // uniform branch (constant data)
    c2 nS, nO, nN;
    if (ilv) {
        nS = {nSi_f[2 * w],    nSi_f[2 * w + 1]};
        nO = {nSiO2_f[2 * w],  nSiO2_f[2 * w + 1]};
        nN = {nSi3N4_f[2 * w], nSi3N4_f[2 * w + 1]};
    } else {
        nS = {nSi_f[w],    0.0f};
        nO = {nSiO2_f[w],  0.0f};
        nN = {nSi3N4_f[w], 0.0f};
    }
    const c2 nA = {1.0f, 0.0f};

    const float k0 = 6.28318530717958647692f / lam[w];

    // Fresnel coefficients: r = (N_prev - N_next)/(N_prev + N_next)
    const c2 rAO  = c_div(c_sub(nA, nO), c_add(nA, nO));  // Air  | SiO2   (interface 1)
    const c2 rON  = c_div(c_sub(nO, nN), c_add(nO, nN));  // SiO2 | Si3N4  (i = 2,4,6)
    const c2 rNO  = {-rON.x, -rON.y};                     // Si3N4| SiO2   (i = 3,5,7)
    const c2 rOSi = c_div(c_sub(nO, nS), c_add(nO, nS));  // SiO2 | Si     (interface 8)

    // k0 * N for the two film materials (layers alternate O,N,O,N,O,N,O)
    const c2 kO = {k0 * nO.x, k0 * nO.y};
    const c2 kN = {k0 * nN.x, k0 * nN.y};

    for (int rr = 0; rr < nrows; ++rr) {
        const float* dd = &sd[rr * 7];

        // Right-to-left vector recurrence: u = T8 * e0 (prefactors cancel in ratio)
        c2 u0 = {1.0f, 0.0f};
        c2 u1 = rOSi;

        #pragma unroll
        for (int i = 7; i >= 1; --i) {
            const float d = dd[i - 1];           // thickness of layer i
            const c2 kk = (i & 1) ? kO : kN;     // layers 1,3,5,7 = SiO2; 2,4,6 = Si3N4
            const float alpha = kk.x * d;        // Re(phi)
            const float beta  = kk.y * d;        // Im(phi)
            float s, c;
            __sincosf(alpha, &s, &c);
            const float ep = __expf(beta);       // |e^{-i phi}|
            const float em = __expf(-beta);      // |e^{+i phi}|

            // u0 *= e^{-i phi} = ep*(c - i s);  u1 *= e^{+i phi} = em*(c + i s)
            c2 v;
            v.x = ep * (u0.x * c + u0.y * s);
            v.y = ep * (u0.y * c - u0.x * s);
            u0 = v;
            v.x = em * (u1.x * c - u1.y * s);
            v.y = em * (u1.y * c + u1.x * s);
            u1 = v;

            // Interface i (inv_t dropped — cancels in final ratio):
            // u0' = u0 + r*u1 ; u1' = r*u0 + u1
            const c2 ri = (i == 1) ? rAO : ((i & 1) ? rNO : rON);
            c2 w0, w1;
            w0.x = u0.x + ri.x * u1.x - ri.y * u1.y;
            w0.y = u0.y + ri.x * u1.y + ri.y * u1.x;
            w1.x = u1.x + ri.x * u0.x - ri.y * u0.y;
            w1.y = u1.y + ri.x * u0.y + ri.y * u0.x;
            u0 = w0; u1 = w1;
        }

        const float R = (u1.x * u1.x + u1.y * u1.y) /
                        (u0.x * u0.x + u0.y * u0.y);
        out[(size_t)(brow0 + rr) * WPTS + w] = R;
    }
}

extern "C" void kernel_launch(void* const* d_in, const int* in_sizes, int n_in,
                              void* d_out, int out_size, void* d_ws, size_t ws_size,
                              hipStream_t stream) {
    const float* d_phys  = (const float*)d_in[0];
    const float* nSi     = (const float*)d_in[1];
    const float* nSiO2   = (const float*)d_in[2];
    const float* nSi3N4  = (const float*)d_in[3];
    const float* lam     = (const float*)d_in[4];
    float* out = (float*)d_out;

    const int B = in_sizes[0] / 7;
    const int grid = (B + ROWS_PER_BLOCK - 1) / ROWS_PER_BLOCK;

    kla_tmm_kernel<<<grid, BLOCK_THREADS, 0, stream>>>(
        d_phys, nSi, nSiO2, nSi3N4, lam, out, B);
}

// Round 3
// 48.548 us; speedup vs baseline: 2.1662x; 2.1662x over previous
//
#include <hip/hip_runtime.h>

#define WPTS 801
#define ROWS 16
#define NT 256

struct c2 { float x, y; };

__device__ __forceinline__ c2 c_add(c2 a, c2 b) { return {a.x + b.x, a.y + b.y}; }
__device__ __forceinline__ c2 c_sub(c2 a, c2 b) { return {a.x - b.x, a.y - b.y}; }
__device__ __forceinline__ c2 c_div(c2 a, c2 b) {
    float inv = 1.0f / (b.x * b.x + b.y * b.y);
    return {(a.x * b.x + a.y * b.y) * inv, (a.y * b.x - a.x * b.y) * inv};
}

__global__ __launch_bounds__(NT)
void kla_tmm_kernel(const float* __restrict__ d_phys,
                    const float* __restrict__ nSi_f,
                    const float* __restrict__ nSiO2_f,
                    const float* __restrict__ nSi3N4_f,
                    const float* __restrict__ lam,
                    float* __restrict__ out,
                    int B)
{
    const int nRowBlks = (B + ROWS - 1) / ROWS;
    const int t = blockIdx.x * NT + threadIdx.x;
    if (t >= nRowBlks * WPTS) return;

    const int w = t % WPTS;
    const int row0 = (t / WPTS) * ROWS;
    const int nrows = min(ROWS, B - row0);

    // ---- Layout-robust complex reads (scalar 4-byte loads; detection
    //      identical to the round-2 kernel that passed) ----
    const bool ilv = (nSiO2_f[1] == 0.0f);
    float nSx, nSy, nOx, nOy, nNx, nNy;
    if (ilv) {
        nSx = nSi_f[2 * w];    nSy = nSi_f[2 * w + 1];
        nOx = nSiO2_f[2 * w];  nOy = nSiO2_f[2 * w + 1];
        nNx = nSi3N4_f[2 * w]; nNy = nSi3N4_f[2 * w + 1];
    } else {
        nSx = nSi_f[w];    nSy = 0.0f;
        nOx = nSiO2_f[w];  nOy = 0.0f;
        nNx = nSi3N4_f[w]; nNy = 0.0f;
    }

    const float k0 = 6.28318530717958647692f / lam[w];

    // Uniform data-driven branch: all-real refractive indices (bench case).
    const bool realn = (nOy == 0.0f) && (nNy == 0.0f) && (nSy == 0.0f);

    if (realn) {
        // ======== real-index fast path: real Fresnel r, |phase|=1 ========
        const float rAO  = (1.0f - nOx) / (1.0f + nOx);
        const float rON  = (nOx - nNx) / (nOx + nNx);
        const float rNO  = -rON;
        const float rOSi = (nOx - nSx) / (nOx + nSx);
        const float kO = k0 * nOx;
        const float kN = k0 * nNx;

        for (int rr = 0; rr < nrows; ++rr) {
            const int row = row0 + rr;
            const float* dd = d_phys + (size_t)row * 7;
            // hoist the 7 thickness loads (same addr across most of the wave)
            float d1 = dd[0], d2 = dd[1], d3 = dd[2], d4 = dd[3],
                  d5 = dd[4], d6 = dd[5], d7 = dd[6];

            float u0x = 1.0f, u0y = 0.0f, u1x = rOSi, u1y = 0.0f;

            #pragma unroll
            for (int i = 7; i >= 1; --i) {
                const float d = (i == 1) ? d1 : (i == 2) ? d2 : (i == 3) ? d3 :
                                (i == 4) ? d4 : (i == 5) ? d5 : (i == 6) ? d6 : d7;
                const float alpha = d * ((i & 1) ? kO : kN);
                float s, c;
                __sincosf(alpha, &s, &c);
                // u0 *= (c - i s); u1 *= (c + i s)
                const float t0x = u0x * c + u0y * s;
                const float t0y = u0y * c - u0x * s;
                const float t1x = u1x * c - u1y * s;
                const float t1y = u1y * c + u1x * s;
                // interface with real r: u0' = u0 + r u1 ; u1' = u1 + r u0
                const float r = (i == 1) ? rAO : ((i & 1) ? rNO : rON);
                u0x = t0x + r * t1x;
                u0y = t0y + r * t1y;
                u1x = t1x + r * t0x;
                u1y = t1y + r * t0y;
            }
            out[(size_t)row * WPTS + w] =
                (u1x * u1x + u1y * u1y) / (u0x * u0x + u0y * u0y);
        }
    } else {
        // ======== general complex path (round-2 code, known correct) ========
        const c2 nA = {1.0f, 0.0f};
        const c2 nO = {nOx, nOy}, nN = {nNx, nNy}, nS = {nSx, nSy};
        const c2 rAO  = c_div(c_sub(nA, nO), c_add(nA, nO));
        const c2 rON  = c_div(c_sub(nO, nN), c_add(nO, nN));
        const c2 rNO  = {-rON.x, -rON.y};
        const c2 rOSi = c_div(c_sub(nO, nS), c_add(nO, nS));
        const c2 kO = {k0 * nO.x, k0 * nO.y};
        const c2 kN = {k0 * nN.x, k0 * nN.y};

        for (int rr = 0; rr < nrows; ++rr) {
            const int row = row0 + rr;
            const float* dd = d_phys + (size_t)row * 7;

            c2 u0 = {1.0f, 0.0f};
            c2 u1 = rOSi;

            #pragma unroll
            for (int i = 7; i >= 1; --i) {
                const float d = dd[i - 1];
                const c2 kk = (i & 1) ? kO : kN;
                const float alpha = kk.x * d;
                const float beta  = kk.y * d;
                float s, c;
                __sincosf(alpha, &s, &c);
                const float ep = __expf(beta);
                const float em = __expf(-beta);

                c2 v;
                v.x = ep * (u0.x * c + u0.y * s);
                v.y = ep * (u0.y * c - u0.x * s);
                u0 = v;
                v.x = em * (u1.x * c - u1.y * s);
                v.y = em * (u1.y * c + u1.x * s);
                u1 = v;

                const c2 ri = (i == 1) ? rAO : ((i & 1) ? rNO : rON);
                c2 w0, w1;
                w0.x = u0.x + ri.x * u1.x - ri.y * u1.y;
                w0.y = u0.y + ri.x * u1.y + ri.y * u1.x;
                w1.x = u1.x + ri.x * u0.x - ri.y * u0.y;
                w1.y = u1.y + ri.x * u0.y + ri.y * u0.x;
                u0 = w0; u1 = w1;
            }

            out[(size_t)row * WPTS + w] =
                (u1.x * u1.x + u1.y * u1.y) / (u0.x * u0.x + u0.y * u0.y);
        }
    }
}

extern "C" void kernel_launch(void* const* d_in, const int* in_sizes, int n_in,
                              void* d_out, int out_size, void* d_ws, size_t ws_size,
                              hipStream_t stream) {
    const float* d_phys  = (const float*)d_in[0];
    const float* nSi     = (const float*)d_in[1];
    const float* nSiO2   = (const float*)d_in[2];
    const float* nSi3N4  = (const float*)d_in[3];
    const float* lam     = (const float*)d_in[4];
    float* out = (float*)d_out;

    const int B = in_sizes[0] / 7;
    const int nRowBlks = (B + ROWS - 1) / ROWS;
    const int nTasks = nRowBlks * WPTS;
    const int grid = (nTasks + NT - 1) / NT;

    kla_tmm_kernel<<<grid, NT, 0, stream>>>(
        d_phys, nSi, nSiO2, nSi3N4, lam, out, B);
}